// Round 6
// baseline (423.084 us; speedup 1.0000x reference)
//
#include <hip/hip_runtime.h>

#define B_SZ   2
#define S_LEN  2048
#define D_DIM  1024
#define V_DIM  32000
#define NTOK   (B_SZ * S_LEN)   // 4096
#define NCYC   8
#define NPLANES 256
#define EPS_F  1.1920929e-07f
#define NTILE  2000             // 16 bm x 125 bn

typedef float  f32x4  __attribute__((ext_vector_type(4)));
typedef __bf16 bf16x8 __attribute__((ext_vector_type(8)));

__device__ __forceinline__ unsigned short f32_to_bf16(float f) {
    unsigned int u = __builtin_bit_cast(unsigned int, f);
    u += 0x7fffu + ((u >> 16) & 1u);   // round-to-nearest-even
    return (unsigned short)(u >> 16);
}

__device__ __forceinline__ float4 mix3(float a, const float4& u, float b,
                                       const float4& v, float c, const float4& w) {
    return make_float4(a * u.x + b * v.x + c * w.x,
                       a * u.y + b * v.y + c * w.y,
                       a * u.z + b * v.z + c * w.z,
                       a * u.w + b * v.w + c * w.w);
}

// ============ per-cycle kernel: block owns tokens 4b..4b+3 =================
__global__ __launch_bounds__(256) void k_cyc(
    int c,
    const int* __restrict__ tokens, const float* __restrict__ table,
    const float* __restrict__ xin, float* __restrict__ xout,
    const float* __restrict__ angles, const float* __restrict__ scales,
    const float* __restrict__ shifts, const float* __restrict__ normw,
    const float* __restrict__ mixw, const float* __restrict__ outnw,
    unsigned short* __restrict__ xbf,
    const int* __restrict__ pi, const int* __restrict__ pj,
    const float* __restrict__ lmhead, unsigned short* __restrict__ wbf)
{
    __shared__ float lx[4][D_DIM];
    __shared__ float red[4][4];   // [wave][token]
    const int b = blockIdx.x, tid = threadIdx.x;
    const int wv = tid >> 6, ln = tid & 63;
    const int t0 = b << 2;
    const int s0 = t0 & (S_LEN - 1);

    float4 row[4];
    float4 hl = make_float4(0.f, 0.f, 0.f, 0.f);
    float4 hr = make_float4(0.f, 0.f, 0.f, 0.f);
    if (c == 0) {
        #pragma unroll
        for (int i = 0; i < 4; ++i) {
            const int tok = tokens[t0 + i];
            row[i] = ((const float4*)(table + (size_t)tok * D_DIM))[tid];
        }
        if (s0 > 0) {
            const int tok = tokens[t0 - 1];
            hl = ((const float4*)(table + (size_t)tok * D_DIM))[tid];
        }
        if (s0 + 4 < S_LEN) {
            const int tok = tokens[t0 + 4];
            hr = ((const float4*)(table + (size_t)tok * D_DIM))[tid];
        }
    } else {
        #pragma unroll
        for (int i = 0; i < 4; ++i)
            row[i] = ((const float4*)(xin + (size_t)(t0 + i) * D_DIM))[tid];
        if (s0 > 0)
            hl = ((const float4*)(xin + (size_t)(t0 - 1) * D_DIM))[tid];
        if (s0 + 4 < S_LEN)
            hr = ((const float4*)(xin + (size_t)(t0 + 4) * D_DIM))[tid];
    }
    const float mw0 = mixw[0], mw1 = mixw[1], mw2 = mixw[2];

    float4 m[4];
    m[0] = mix3(mw0, hl,     mw1, row[0], mw2, row[1]);
    m[1] = mix3(mw0, row[0], mw1, row[1], mw2, row[2]);
    m[2] = mix3(mw0, row[1], mw1, row[2], mw2, row[3]);
    m[3] = mix3(mw0, row[2], mw1, row[3], mw2, hr);
    #pragma unroll
    for (int i = 0; i < 4; ++i) ((float4*)lx[i])[tid] = m[i];
    __syncthreads();

    const int ip = pi[tid], jp = pj[tid];
    float sa, ca;
    sincosf(angles[tid], &sa, &ca);
    float xi[4], xj[4];
    #pragma unroll
    for (int i = 0; i < 4; ++i) { xi[i] = lx[i][ip]; xj[i] = lx[i][jp]; }
    #pragma unroll
    for (int i = 0; i < 4; ++i) {
        lx[i][ip] = xi[i] * ca - xj[i] * sa;
        lx[i][jp] = xi[i] * sa + xj[i] * ca;
    }
    __syncthreads();

    const float4 sc = ((const float4*)scales)[tid];
    const float4 sh = ((const float4*)shifts)[tid];
    const float4 nw = ((const float4*)normw)[tid];
    float4 r[4];
    float sum[4];
    #pragma unroll
    for (int i = 0; i < 4; ++i) {
        const float4 xn = ((const float4*)lx[i])[tid];
        const float a0 = xn.x * sc.x + sh.x;
        const float a1 = xn.y * sc.y + sh.y;
        const float a2 = xn.z * sc.z + sh.z;
        const float a3 = xn.w * sc.w + sh.w;
        r[i].x = a0 / (1.f + expf(-a0)) - m[i].x;
        r[i].y = a1 / (1.f + expf(-a1)) - m[i].y;
        r[i].z = a2 / (1.f + expf(-a2)) - m[i].z;
        r[i].w = a3 / (1.f + expf(-a3)) - m[i].w;
        sum[i] = r[i].x * r[i].x + r[i].y * r[i].y
               + r[i].z * r[i].z + r[i].w * r[i].w;
    }
    #pragma unroll
    for (int off = 32; off > 0; off >>= 1)
        #pragma unroll
        for (int i = 0; i < 4; ++i) sum[i] += __shfl_down(sum[i], off, 64);
    if (ln == 0) {
        red[wv][0] = sum[0]; red[wv][1] = sum[1];
        red[wv][2] = sum[2]; red[wv][3] = sum[3];
    }
    __syncthreads();
    #pragma unroll
    for (int i = 0; i < 4; ++i) {
        const float tot = red[0][i] + red[1][i] + red[2][i] + red[3][i];
        const float inv = rsqrtf(tot * (1.0f / D_DIM) + EPS_F);
        row[i].x = m[i].x + r[i].x * inv * nw.x;
        row[i].y = m[i].y + r[i].y * inv * nw.y;
        row[i].z = m[i].z + r[i].z * inv * nw.z;
        row[i].w = m[i].w + r[i].w * inv * nw.w;
    }

    if (c == 7) {
        __syncthreads();
        float fs[4];
        #pragma unroll
        for (int i = 0; i < 4; ++i)
            fs[i] = row[i].x * row[i].x + row[i].y * row[i].y
                  + row[i].z * row[i].z + row[i].w * row[i].w;
        #pragma unroll
        for (int off = 32; off > 0; off >>= 1)
            #pragma unroll
            for (int i = 0; i < 4; ++i) fs[i] += __shfl_down(fs[i], off, 64);
        if (ln == 0) {
            red[wv][0] = fs[0]; red[wv][1] = fs[1];
            red[wv][2] = fs[2]; red[wv][3] = fs[3];
        }
        __syncthreads();
        const float4 w = ((const float4*)outnw)[tid];
        #pragma unroll
        for (int i = 0; i < 4; ++i) {
            const float tot = red[0][i] + red[1][i] + red[2][i] + red[3][i];
            const float inv = rsqrtf(tot * (1.0f / D_DIM) + EPS_F);
            const ushort4 o = make_ushort4(f32_to_bf16(row[i].x * inv * w.x),
                                           f32_to_bf16(row[i].y * inv * w.y),
                                           f32_to_bf16(row[i].z * inv * w.z),
                                           f32_to_bf16(row[i].w * inv * w.w));
            ((ushort4*)xbf)[(size_t)(t0 + i) * 256 + tid] = o;
        }
    } else {
        #pragma unroll
        for (int i = 0; i < 4; ++i)
            ((float4*)(xout + (size_t)(t0 + i) * D_DIM))[tid] = row[i];
    }

    // lm_head fp32->bf16 slice for this cycle
    {
        const int end = (c + 1) * 1024000;
        for (int i = c * 1024000 + b * 256 + tid; i < end; i += 262144) {
            const float4 v = ((const float4*)lmhead)[i];
            const ushort4 o = make_ushort4(f32_to_bf16(v.x), f32_to_bf16(v.y),
                                           f32_to_bf16(v.z), f32_to_bf16(v.w));
            ((ushort4*)wbf)[i] = o;
        }
    }
}

// ====== persistent GEMM: 256x256 tile, BK=64, 8-phase, XCD-grouped tiles ===
// 256 blocks, 1/CU. XCD x (= bid&7) owns tiles [x*250, (x+1)*250); block
// r (= bid>>3) walks contiguous run T = x*250 + r*8 + k (r<31: 8 tiles,
// r==31: 2). Consecutive T walk bm fastest -> each 512 KB B panel is read
// by ONE XCD and stays in its L2; stage loads hit L2 (~200cy) not HBM.
// Cross-tile seam: j==7's k2/k3 stages use the next tile's base pointers.
#define GLD_LDS(g, l)                                                          \
    __builtin_amdgcn_global_load_lds(                                          \
        (const __attribute__((address_space(1))) void*)(g),                    \
        (__attribute__((address_space(3))) void*)(l), 16, 0, 0)

#define STAGE_A(BUF, H, KT, P) do {                                            \
    GLD_LDS((P) + (size_t)(H) * 131072 + (size_t)(KT) * 64,                    \
            &lds[(BUF) * 32768 + (H) * 8192 + wave * 1024]);                   \
    GLD_LDS((P) + (size_t)(H) * 131072 + 8192 + (size_t)(KT) * 64,             \
            &lds[(BUF) * 32768 + (H) * 8192 + wave * 1024 + 512]);             \
} while (0)

#define STAGE_B(BUF, H, KT, P) do {                                            \
    GLD_LDS((P) + (size_t)(H) * 131072 + (size_t)(KT) * 64,                    \
            &lds[16384 + (BUF) * 32768 + (H) * 8192 + wave * 1024]);           \
    GLD_LDS((P) + (size_t)(H) * 131072 + 8192 + (size_t)(KT) * 64,             \
            &lds[16384 + (BUF) * 32768 + (H) * 8192 + wave * 1024 + 512]);     \
} while (0)

#define RD_A(BUF, MIB) do { _Pragma("unroll")                                  \
    for (int q_ = 0; q_ < 4; ++q_) {                                           \
        afr[q_][0] = *(const bf16x8*)&lds[(BUF) * 32768 + aoff + ((MIB) + q_) * 1024 + kx0]; \
        afr[q_][1] = *(const bf16x8*)&lds[(BUF) * 32768 + aoff + ((MIB) + q_) * 1024 + kx1]; \
    } } while (0)

#define RD_B(BUF, NIB, DST) do { _Pragma("unroll")                             \
    for (int n_ = 0; n_ < 2; ++n_) {                                           \
        DST[n_][0] = *(const bf16x8*)&lds[(BUF) * 32768 + boff + ((NIB) + n_) * 1024 + kx0]; \
        DST[n_][1] = *(const bf16x8*)&lds[(BUF) * 32768 + boff + ((NIB) + n_) * 1024 + kx1]; \
    } } while (0)

#define MFMA16(MIB, NIB, BF) do {                                              \
    __builtin_amdgcn_s_setprio(1);                                             \
    _Pragma("unroll") for (int m_ = 0; m_ < 4; ++m_)                           \
    _Pragma("unroll") for (int n_ = 0; n_ < 2; ++n_) {                         \
        acc[(MIB) + m_][(NIB) + n_] = __builtin_amdgcn_mfma_f32_16x16x32_bf16( \
            afr[m_][0], BF[n_][0], acc[(MIB) + m_][(NIB) + n_], 0, 0, 0);      \
        acc[(MIB) + m_][(NIB) + n_] = __builtin_amdgcn_mfma_f32_16x16x32_bf16( \
            afr[m_][1], BF[n_][1], acc[(MIB) + m_][(NIB) + n_], 0, 0, 0);      \
    }                                                                          \
    __builtin_amdgcn_s_setprio(0); } while (0)

#define PH_SYNC() do { __builtin_amdgcn_s_barrier();                           \
    asm volatile("s_waitcnt lgkmcnt(0)" ::: "memory"); } while (0)
#define PH_END() do { asm volatile("" ::: "memory");                           \
    __builtin_amdgcn_s_barrier(); } while (0)
#define VMCNT4() asm volatile("s_waitcnt vmcnt(4)" ::: "memory")

__global__ __launch_bounds__(512, 2) void k_gemm(
    const unsigned short* __restrict__ A,   // [NTOK, 1024] bf16 bits
    const unsigned short* __restrict__ Bw,  // [V, 1024]    bf16 bits
    float* __restrict__ C)                  // [NTOK, V]    fp32
{
    __shared__ __align__(16) unsigned short lds[65536];   // 128 KiB
    const int tid = threadIdx.x;
    const int wave = tid >> 6, lane = tid & 63;
    const int wm = wave >> 2, wn = wave & 3;
    const int lr = lane & 15, kg = lane >> 4;

    const int xr  = (lane & 7) * 8;
    const int kx0 = (kg * 8) ^ xr;
    const int kx1 = (32 + kg * 8) ^ xr;
    const int aoff = (wm * 128 + lr) * 64;
    const int boff = 16384 + (wn * 64 + lr) * 64;

    const int srow = lane >> 3;
    const int scol = ((lane & 7) ^ srow) * 8;   // pre-swizzled source col
    const int soff = (wave * 16 + srow) * 1024 + scol;

    // XCD-grouped persistent mapping
    const int xcd = blockIdx.x & 7;
    const int rr  = blockIdx.x >> 3;            // 0..31
    const int tbase = xcd * 250 + rr * 8;
    const int ntile_mine = (rr == 31) ? 2 : 8;  // 31*8+2 = 250 per XCD

    int T  = tbase;
    int bm = T & 15, bn = T >> 4;
    const unsigned short* gA = A  + (size_t)(bm * 256) * 1024 + soff;
    const unsigned short* gB = Bw + (size_t)(bn * 256) * 1024 + soff;

    bf16x8 afr[4][2], b01[2][2], b23[2][2];

    // prologue (once per block)
    STAGE_A(0, 0, 0, gA); STAGE_A(0, 1, 0, gA);
    STAGE_B(0, 0, 0, gB); STAGE_B(0, 1, 0, gB);
    STAGE_B(1, 0, 1, gB); STAGE_B(1, 1, 1, gB);
    VMCNT4();
    __builtin_amdgcn_s_barrier();

    for (int t = 0; t < ntile_mine; ++t) {
        const bool last = (t == ntile_mine - 1);
        const int Tn = last ? T : T + 1;         // clamp: redundant restage
        const int bm2 = Tn & 15, bn2 = Tn >> 4;
        const unsigned short* gA2 = A  + (size_t)(bm2 * 256) * 1024 + soff;
        const unsigned short* gB2 = Bw + (size_t)(bn2 * 256) * 1024 + soff;

        f32x4 acc[8][4];
        #pragma unroll
        for (int i = 0; i < 8; ++i)
            #pragma unroll
            for (int j2 = 0; j2 < 4; ++j2) acc[i][j2] = (f32x4){0.f, 0.f, 0.f, 0.f};

        for (int j = 0; j < 8; ++j) {
            const unsigned short* sA = (j == 7) ? gA2 : gA;
            const unsigned short* sB = (j == 7) ? gB2 : gB;
            const int k1 = 2 * j + 1;          // current tile, <=15
            const int k2 = (2 * j + 2) & 15;   // wraps to 0 at j==7 (next tile)
            const int k3 = (2 * j + 3) & 15;   // wraps to 1 at j==7 (next tile)

            RD_A(0, 0); RD_B(0, 0, b01);
            STAGE_A(1, 0, k1, gA);
            PH_SYNC(); MFMA16(0, 0, b01); PH_END();

            RD_B(0, 2, b23);
            STAGE_A(1, 1, k1, gA);
            PH_SYNC(); MFMA16(0, 2, b23); PH_END();

            RD_A(0, 4);
            STAGE_B(0, 0, k2, sB);
            PH_SYNC(); MFMA16(4, 2, b23); PH_END();

            STAGE_B(0, 1, k2, sB);
            VMCNT4();
            PH_SYNC(); MFMA16(4, 0, b01); PH_END();

            RD_A(1, 0); RD_B(1, 0, b01);
            STAGE_A(0, 0, k2, sA);
            PH_SYNC(); MFMA16(0, 0, b01); PH_END();

            RD_B(1, 2, b23);
            STAGE_A(0, 1, k2, sA);
            PH_SYNC(); MFMA16(0, 2, b23); PH_END();

            RD_A(1, 4);
            STAGE_B(1, 0, k3, sB);
            PH_SYNC(); MFMA16(4, 2, b23); PH_END();

            STAGE_B(1, 1, k3, sB);
            VMCNT4();
            PH_SYNC(); MFMA16(4, 0, b01); PH_END();
        }

        // epilogue: plain stores (L2-merged)
        #pragma unroll
        for (int mi = 0; mi < 8; ++mi) {
            const size_t m0 = (size_t)(bm * 256 + wm * 128 + mi * 16 + kg * 4);
            #pragma unroll
            for (int ni = 0; ni < 4; ++ni) {
                const int n = bn * 256 + wn * 64 + ni * 16 + lr;
                float* cp = C + m0 * V_DIM + n;
                cp[0]                 = acc[mi][ni][0];
                cp[(size_t)V_DIM]     = acc[mi][ni][1];
                cp[(size_t)2 * V_DIM] = acc[mi][ni][2];
                cp[(size_t)3 * V_DIM] = acc[mi][ni][3];
            }
        }

        T = Tn; bm = bm2; bn = bn2; gA = gA2; gB = gB2;
    }
}

extern "C" void kernel_launch(void* const* d_in, const int* in_sizes, int n_in,
                              void* d_out, int out_size, void* d_ws, size_t ws_size,
                              hipStream_t stream)
{
    const int*   tokens = (const int*)  d_in[0];
    const float* embedw = (const float*)d_in[1];
    const float* angles = (const float*)d_in[2];
    const float* scales = (const float*)d_in[3];
    const float* shifts = (const float*)d_in[4];
    const float* normw  = (const float*)d_in[5];
    const float* mixw   = (const float*)d_in[6];
    const float* outnw  = (const float*)d_in[7];
    const float* lmhead = (const float*)d_in[8];
    const int*   pi_all = (const int*)  d_in[9];
    const int*   pj_all = (const int*)  d_in[10];
    float* out = (float*)d_out;

    float* xa = (float*)d_ws;
    float* xb = xa + (size_t)NTOK * D_DIM;
    unsigned short* xbf = (unsigned short*)(xb + (size_t)NTOK * D_DIM);
    unsigned short* wbf = xbf + (size_t)NTOK * D_DIM;

    for (int c = 0; c < NCYC; ++c) {
        const float* xin = (c & 1) ? xb : xa;
        float* xout = (c & 1) ? xa : xb;
        k_cyc<<<NTOK / 4, 256, 0, stream>>>(c, tokens, embedw, xin, xout,
            angles + c * NPLANES, scales + c * D_DIM, shifts + c * D_DIM,
            normw + c * D_DIM, mixw, outnw, xbf,
            pi_all + c * NPLANES, pj_all + c * NPLANES, lmhead, wbf);
    }

    k_gemm<<<256, 512, 0, stream>>>(xbf, wbf, out);
}